// Round 3
// baseline (627.756 us; speedup 1.0000x reference)
//
#include <hip/hip_runtime.h>

#define NN 50000
#define NE 800000
#define GN 32                       // nodes per gemm block
#define NB1 196                     // ceil(NN/256) scan blocks
#define NBD3 391                    // ceil(NN/128) dense3 blocks
#define NBGEMM 1563                 // ceil(NN/GN)
#define PMAX (NBGEMM*128)           // offset of max-partials in part buffer

__device__ __forceinline__ float elu_f(float x){ return x > 0.f ? x : __expf(x) - 1.f; }

__device__ __forceinline__ void fma4(float4& a, float s, const float4& w){
    a.x += s*w.x; a.y += s*w.y; a.z += s*w.z; a.w += s*w.w;
}
__device__ __forceinline__ void add4(float4& a, const float4& w){
    a.x += w.x; a.y += w.y; a.z += w.z; a.w += w.w;
}
__device__ __forceinline__ void max4(float4& a, const float4& w){
    a.x = fmaxf(a.x,w.x); a.y = fmaxf(a.y,w.y); a.z = fmaxf(a.z,w.z); a.w = fmaxf(a.w,w.w);
}

// ======== CSR build (by destination col) ========
__global__ void k_hist(const int* __restrict__ col, int* __restrict__ deg){
    int e = blockIdx.x * blockDim.x + threadIdx.x;
    if (e >= NE) return;
    atomicAdd(&deg[col[e]], 1);
}

// phase A: per-block sums of deg
__global__ __launch_bounds__(256) void k_psum(const int* __restrict__ deg, int* __restrict__ bsum){
    __shared__ int red[256];
    int i = blockIdx.x*256 + threadIdx.x;
    red[threadIdx.x] = (i < NN) ? deg[i] : 0;
    __syncthreads();
    for (int off = 128; off > 0; off >>= 1){
        if (threadIdx.x < off) red[threadIdx.x] += red[threadIdx.x + off];
        __syncthreads();
    }
    if (threadIdx.x == 0) bsum[blockIdx.x] = red[0];
}

// phase B: scan 196 block sums (one small block)
__global__ __launch_bounds__(256) void k_pscan(const int* __restrict__ bsum, int* __restrict__ boff,
                                               int* __restrict__ rowptr){
    __shared__ int s[256];
    int t = threadIdx.x;
    int v = (t < NB1) ? bsum[t] : 0;
    s[t] = v;
    __syncthreads();
    for (int off = 1; off < 256; off <<= 1){
        int u = (t >= off) ? s[t - off] : 0;
        __syncthreads();
        s[t] += u;
        __syncthreads();
    }
    if (t < NB1) boff[t] = s[t] - v;        // exclusive
    if (t == 255) rowptr[NN] = s[255];      // total = NE
}

// phase C: in-block scan + offset -> rowptr
__global__ __launch_bounds__(256) void k_rowptr(const int* __restrict__ deg, const int* __restrict__ boff,
                                                int* __restrict__ rowptr){
    __shared__ int s[256];
    int t = threadIdx.x;
    int i = blockIdx.x*256 + t;
    int v = (i < NN) ? deg[i] : 0;
    s[t] = v;
    __syncthreads();
    for (int off = 1; off < 256; off <<= 1){
        int u = (t >= off) ? s[t - off] : 0;
        __syncthreads();
        s[t] += u;
        __syncthreads();
    }
    if (i < NN) rowptr[i] = boff[blockIdx.x] + s[t] - v;
}

// fill CSR: per edge, packed {src, norm}
__global__ void k_fill(const int* __restrict__ row, const int* __restrict__ col,
                       const float* __restrict__ dis, const int* __restrict__ rowptr,
                       int* __restrict__ cursor, int2* __restrict__ edge){
    int e = blockIdx.x * blockDim.x + threadIdx.x;
    if (e >= NE) return;
    int r = row[e], c = col[e];
    int idx = rowptr[c] + atomicAdd(&cursor[c], 1);
    edge[idx] = make_int2(r, __float_as_int(dis[r] * dis[c]));
}

// ======== layer 1: gather 3-channel, thread per node ========
__global__ void k_gather3(const float* __restrict__ x, const int* __restrict__ rowptr,
                          const int2* __restrict__ edge, float* __restrict__ agg){
    int n = blockIdx.x * blockDim.x + threadIdx.x;
    if (n >= NN) return;
    int j0 = rowptr[n], j1 = rowptr[n + 1];
    float a0 = 0.f, a1 = 0.f, a2 = 0.f;
    for (int j = j0; j < j1; ++j){
        int2 e = edge[j];
        int r = e.x; float w = __int_as_float(e.y);
        a0 = fmaf(x[r*3+0], w, a0);
        a1 = fmaf(x[r*3+1], w, a1);
        a2 = fmaf(x[r*3+2], w, a2);
    }
    agg[n*3+0] = a0; agg[n*3+1] = a1; agg[n*3+2] = a2;
}

// ---- layer 1 dense + fused pool: channel per thread, 128 nodes per block ----
__global__ __launch_bounds__(128) void k_dense3p(const float* __restrict__ agg, const float* __restrict__ W,
                          const float* __restrict__ b, float* __restrict__ h, float* __restrict__ part){
    int c = threadIdx.x;
    int n0 = blockIdx.x * 128;
    int n1 = min(n0 + 128, NN);
    float w0 = W[c*3+0], w1 = W[c*3+1], w2 = W[c*3+2], bb = b[c];
    float s = 0.f, m = -3.4e38f;
    for (int n = n0; n < n1; ++n){
        float v = fmaf(agg[n*3+0], w0, fmaf(agg[n*3+1], w1, fmaf(agg[n*3+2], w2, bb)));
        v = elu_f(v);
        h[(size_t)n*128 + c] = v;
        s += v; m = fmaxf(m, v);
    }
    part[blockIdx.x*128 + c] = s;
    part[PMAX + blockIdx.x*128 + c] = m;
}

// ======== 128-channel gather: agg[n] = att * sum_j h[src[j]] * nrm[j] ========
__global__ __launch_bounds__(256) void k_gather128(const float* __restrict__ h,
                              const int* __restrict__ rowptr, const int2* __restrict__ edge,
                              const float* __restrict__ att, float* __restrict__ agg){
    int t = blockIdx.x * blockDim.x + threadIdx.x;
    int n = t >> 5, l = t & 31;
    if (n >= NN) return;
    int j0 = rowptr[n], j1 = rowptr[n + 1];
    float4 acc = {0.f, 0.f, 0.f, 0.f};
    int j = j0;
    for (; j + 3 < j1; j += 4){
        int2 e0 = edge[j], e1 = edge[j+1], e2 = edge[j+2], e3 = edge[j+3];
        float4 v0 = ((const float4*)(h + (size_t)e0.x*128))[l];
        float4 v1 = ((const float4*)(h + (size_t)e1.x*128))[l];
        float4 v2 = ((const float4*)(h + (size_t)e2.x*128))[l];
        float4 v3 = ((const float4*)(h + (size_t)e3.x*128))[l];
        fma4(acc, __int_as_float(e0.y), v0);
        fma4(acc, __int_as_float(e1.y), v1);
        fma4(acc, __int_as_float(e2.y), v2);
        fma4(acc, __int_as_float(e3.y), v3);
    }
    for (; j < j1; ++j){
        int2 e0 = edge[j];
        float4 v0 = ((const float4*)(h + (size_t)e0.x*128))[l];
        fma4(acc, __int_as_float(e0.y), v0);
    }
    float4 a = ((const float4*)att)[l];
    acc.x *= a.x; acc.y *= a.y; acc.z *= a.z; acc.w *= a.w;
    ((float4*)(agg + (size_t)n*128))[l] = acc;
}

// ---- channel attention MLP: att = sigmoid(mlp(avg)+mlp(max)) ----
__global__ __launch_bounds__(512) void k_attn(const float* __restrict__ part, int nblk,
                       const float* __restrict__ w1, const float* __restrict__ w2,
                       float* __restrict__ att){
    __shared__ float sAll[4][128], mAll[4][128];
    __shared__ float avg[128], mx[128], ha[8], hm[8];
    int c = threadIdx.x & 127, g = threadIdx.x >> 7;
    float s = 0.f, m = -3.4e38f;
    for (int b = g; b < nblk; b += 4){
        s += part[b*128 + c];
        m = fmaxf(m, part[PMAX + b*128 + c]);
    }
    sAll[g][c] = s; mAll[g][c] = m;
    __syncthreads();
    if (g == 0){
        s = sAll[0][c] + sAll[1][c] + sAll[2][c] + sAll[3][c];
        m = fmaxf(fmaxf(mAll[0][c], mAll[1][c]), fmaxf(mAll[2][c], mAll[3][c]));
        avg[c] = s / (float)NN;
        mx[c] = m;
    }
    __syncthreads();
    if (threadIdx.x < 8){
        int cc = threadIdx.x;
        float sa = 0.f, sm = 0.f;
        for (int k = 0; k < 128; ++k){
            float w = w1[cc*128 + k];
            sa += avg[k]*w; sm += mx[k]*w;
        }
        ha[cc] = fmaxf(sa, 0.f); hm[cc] = fmaxf(sm, 0.f);
    }
    __syncthreads();
    if (threadIdx.x < 128){
        float oa = 0.f, om = 0.f;
        for (int j = 0; j < 8; ++j){
            float w = w2[c*8 + j];
            oa += ha[j]*w; om += hm[j]*w;
        }
        att[c] = 1.f / (1.f + __expf(-(oa + om)));
    }
}

// ---- dense: out = ELU(A @ W^T + b) + fused pool partials ----
__global__ __launch_bounds__(256) void k_gemm128(const float* __restrict__ A, const float* __restrict__ W,
                         const float* __restrict__ b, float* __restrict__ out, float* __restrict__ part){
    __shared__ float4 WtV[128*32];   // swizzled transposed W
    __shared__ float At[GN*128];
    int tid = threadIdx.x;
    float* Wt = (float*)WtV;
    for (int i = tid; i < 128*128; i += 256){
        int j = i >> 7, cc = i & 127;
        int slot = (cc*32 + (((j>>2) + cc) & 31))*4 + (j&3);
        Wt[slot] = W[i];
    }
    int n0 = blockIdx.x * GN;
    for (int i = tid; i < GN*128; i += 256){
        int n = n0 + (i >> 7);
        At[i] = (n < NN) ? A[(size_t)n*128 + (i & 127)] : 0.f;
    }
    __syncthreads();
    int jg = tid & 31, ng = tid >> 5;   // channels 4jg..+3, nodes ng*4..+3
    float4 bv = ((const float4*)b)[jg];
    float4 acc0 = bv, acc1 = bv, acc2 = bv, acc3 = bv;
    const float4* A0 = (const float4*)(At + (ng*4+0)*128);
    const float4* A1 = (const float4*)(At + (ng*4+1)*128);
    const float4* A2 = (const float4*)(At + (ng*4+2)*128);
    const float4* A3 = (const float4*)(At + (ng*4+3)*128);
    #pragma unroll 4
    for (int c4 = 0; c4 < 32; ++c4){
        int cb = c4*4;
        float4 w0 = WtV[(cb+0)*32 + ((jg + cb+0)&31)];
        float4 w1 = WtV[(cb+1)*32 + ((jg + cb+1)&31)];
        float4 w2 = WtV[(cb+2)*32 + ((jg + cb+2)&31)];
        float4 w3 = WtV[(cb+3)*32 + ((jg + cb+3)&31)];
        float4 a;
        a = A0[c4]; fma4(acc0,a.x,w0); fma4(acc0,a.y,w1); fma4(acc0,a.z,w2); fma4(acc0,a.w,w3);
        a = A1[c4]; fma4(acc1,a.x,w0); fma4(acc1,a.y,w1); fma4(acc1,a.z,w2); fma4(acc1,a.w,w3);
        a = A2[c4]; fma4(acc2,a.x,w0); fma4(acc2,a.y,w1); fma4(acc2,a.z,w2); fma4(acc2,a.w,w3);
        a = A3[c4]; fma4(acc3,a.x,w0); fma4(acc3,a.y,w1); fma4(acc3,a.z,w2); fma4(acc3,a.w,w3);
    }
    float4 accs[4] = {acc0, acc1, acc2, acc3};
    float4 s4 = {0.f,0.f,0.f,0.f};
    float4 m4 = {-3.4e38f,-3.4e38f,-3.4e38f,-3.4e38f};
    #pragma unroll
    for (int k = 0; k < 4; ++k){
        int n = n0 + ng*4 + k;
        float4 v = accs[k];
        v.x = elu_f(v.x); v.y = elu_f(v.y); v.z = elu_f(v.z); v.w = elu_f(v.w);
        if (n < NN){
            ((float4*)(out + (size_t)n*128))[jg] = v;
            add4(s4, v); max4(m4, v);
        }
    }
    // pool reduce across ng groups (reuse At as scratch)
    __syncthreads();
    float4* reds = (float4*)At;          // [8][32]
    float4* redm = reds + 256;           // [8][32]
    reds[ng*32 + jg] = s4;
    redm[ng*32 + jg] = m4;
    __syncthreads();
    if (tid < 32){
        float4 S = {0.f,0.f,0.f,0.f};
        float4 M = {-3.4e38f,-3.4e38f,-3.4e38f,-3.4e38f};
        #pragma unroll
        for (int g = 0; g < 8; ++g){ add4(S, reds[g*32 + tid]); max4(M, redm[g*32 + tid]); }
        ((float4*)(part + blockIdx.x*128))[tid] = S;
        ((float4*)(part + PMAX + blockIdx.x*128))[tid] = M;
    }
}

// ---- output head: out[n,k] = sum_c h[n,c]*att[c]*Wout[k,c] + bout[k] ----
__global__ void k_out(const float* __restrict__ h, const float* __restrict__ att,
                      const float* __restrict__ Wo, const float* __restrict__ bo,
                      float* __restrict__ out){
    int t = blockIdx.x * blockDim.x + threadIdx.x;
    if (t >= NN*3) return;
    int n = t / 3, k = t - n*3;
    const float4* hv = (const float4*)(h + (size_t)n*128);
    const float4* av = (const float4*)att;
    const float4* wv = (const float4*)(Wo + k*128);
    float acc = bo[k];
    #pragma unroll 8
    for (int i = 0; i < 32; ++i){
        float4 hh = hv[i], aa = av[i], ww = wv[i];
        acc += hh.x*aa.x*ww.x + hh.y*aa.y*ww.y + hh.z*aa.z*ww.z + hh.w*aa.w*ww.w;
    }
    out[t] = acc;
}

extern "C" void kernel_launch(void* const* d_in, const int* in_sizes, int n_in,
                              void* d_out, int out_size, void* d_ws, size_t ws_size,
                              hipStream_t stream) {
    const float* x    = (const float*)d_in[0];
    const int*   ei   = (const int*)d_in[1];
    const int*   row  = ei;
    const int*   col  = ei + NE;
    const float* dis  = (const float*)d_in[2];
    const float* W1   = (const float*)d_in[3];
    const float* b1   = (const float*)d_in[4];
    const float* W2   = (const float*)d_in[5];
    const float* b2   = (const float*)d_in[6];
    const float* W3   = (const float*)d_in[7];
    const float* b3   = (const float*)d_in[8];
    const float* ca1w1= (const float*)d_in[9];
    const float* ca1w2= (const float*)d_in[10];
    const float* ca2w1= (const float*)d_in[11];
    const float* ca2w2= (const float*)d_in[12];
    const float* ca3w1= (const float*)d_in[13];
    const float* ca3w2= (const float*)d_in[14];
    const float* Wout = (const float*)d_in[15];
    const float* bout = (const float*)d_in[16];
    float* out = (float*)d_out;

    float* bufA = (float*)d_ws;                         // [N,128]
    float* bufB = bufA + (size_t)NN*128;                // [N,128]; first 150K also used as agg3
    float* part = bufB + (size_t)NN*128;                // 2*NBGEMM*128
    float* att1 = part + (size_t)2*PMAX;
    float* att2 = att1 + 128;
    float* att3 = att2 + 128;
    int2*  edge = (int2*)(att3 + 128);                  // [NE] {src, norm}
    int*   rowptr = (int*)(edge + NE);                  // [NN+1]
    int*   deg  = rowptr + NN + 1;                      // [NN]
    int*   cursor = deg + NN;                           // [NN]
    int*   bsum = cursor + NN;                          // [NB1]
    int*   boff = bsum + NB1;                           // [NB1]

    const int gath_blocks = (NN * 32 + 255) / 256;

    // ---- CSR build (reused by all 3 layers) ----
    hipMemsetAsync(deg, 0, (size_t)NN * 2 * sizeof(int), stream);   // deg + cursor
    k_hist<<<(NE+255)/256, 256, 0, stream>>>(col, deg);
    k_psum<<<NB1, 256, 0, stream>>>(deg, bsum);
    k_pscan<<<1, 256, 0, stream>>>(bsum, boff, rowptr);
    k_rowptr<<<NB1, 256, 0, stream>>>(deg, boff, rowptr);
    k_fill<<<(NE+255)/256, 256, 0, stream>>>(row, col, dis, rowptr, cursor, edge);

    // ---- layer 1 ----
    k_gather3<<<(NN+255)/256, 256, 0, stream>>>(x, rowptr, edge, bufB);
    k_dense3p<<<NBD3, 128, 0, stream>>>(bufB, W1, b1, bufA, part);
    k_attn<<<1, 512, 0, stream>>>(part, NBD3, ca1w1, ca1w2, att1);

    // ---- layer 2 ----
    k_gather128<<<gath_blocks, 256, 0, stream>>>(bufA, rowptr, edge, att1, bufB);
    k_gemm128<<<NBGEMM, 256, 0, stream>>>(bufB, W2, b2, bufA, part);
    k_attn<<<1, 512, 0, stream>>>(part, NBGEMM, ca2w1, ca2w2, att2);

    // ---- layer 3 ----
    k_gather128<<<gath_blocks, 256, 0, stream>>>(bufA, rowptr, edge, att2, bufB);
    k_gemm128<<<NBGEMM, 256, 0, stream>>>(bufB, W3, b3, bufA, part);
    k_attn<<<1, 512, 0, stream>>>(part, NBGEMM, ca3w1, ca3w2, att3);

    // ---- output head (att3 folded in) ----
    k_out<<<(NN*3 + 255)/256, 256, 0, stream>>>(bufA, att3, Wout, bout, out);
}

// Round 4
// 398.771 us; speedup vs baseline: 1.5742x; 1.5742x over previous
//
#include <hip/hip_runtime.h>

#define NN 50000
#define NE 800000
#define GN 32                       // nodes per gemm block
#define NB1 196                     // ceil(NN/256) scan blocks
#define NBD3 391                    // ceil(NN/128) dense3 blocks
#define NBGEMM 1563                 // ceil(NN/GN)
#define PMAX (NBGEMM*128)           // offset of max-partials in part buffer
#define NRED 64                     // reduced partial rows after k_attn_pre

__device__ __forceinline__ float elu_f(float x){ return x > 0.f ? x : __expf(x) - 1.f; }

__device__ __forceinline__ void fma4(float4& a, float s, const float4& w){
    a.x += s*w.x; a.y += s*w.y; a.z += s*w.z; a.w += s*w.w;
}
__device__ __forceinline__ void add4(float4& a, const float4& w){
    a.x += w.x; a.y += w.y; a.z += w.z; a.w += w.w;
}
__device__ __forceinline__ void max4(float4& a, const float4& w){
    a.x = fmaxf(a.x,w.x); a.y = fmaxf(a.y,w.y); a.z = fmaxf(a.z,w.z); a.w = fmaxf(a.w,w.w);
}

// ======== CSR build (by destination col) ========
__global__ void k_hist(const int* __restrict__ col, int* __restrict__ deg){
    int e = blockIdx.x * blockDim.x + threadIdx.x;
    if (e >= NE) return;
    atomicAdd(&deg[col[e]], 1);
}

// phase A: per-block sums of deg
__global__ __launch_bounds__(256) void k_psum(const int* __restrict__ deg, int* __restrict__ bsum){
    __shared__ int red[256];
    int i = blockIdx.x*256 + threadIdx.x;
    red[threadIdx.x] = (i < NN) ? deg[i] : 0;
    __syncthreads();
    for (int off = 128; off > 0; off >>= 1){
        if (threadIdx.x < off) red[threadIdx.x] += red[threadIdx.x + off];
        __syncthreads();
    }
    if (threadIdx.x == 0) bsum[blockIdx.x] = red[0];
}

// phase B: scan 196 block sums (one small block)
__global__ __launch_bounds__(256) void k_pscan(const int* __restrict__ bsum, int* __restrict__ boff,
                                               int* __restrict__ rowptr){
    __shared__ int s[256];
    int t = threadIdx.x;
    int v = (t < NB1) ? bsum[t] : 0;
    s[t] = v;
    __syncthreads();
    for (int off = 1; off < 256; off <<= 1){
        int u = (t >= off) ? s[t - off] : 0;
        __syncthreads();
        s[t] += u;
        __syncthreads();
    }
    if (t < NB1) boff[t] = s[t] - v;        // exclusive
    if (t == 255) rowptr[NN] = s[255];      // total = NE
}

// phase C: in-block scan + offset -> rowptr
__global__ __launch_bounds__(256) void k_rowptr(const int* __restrict__ deg, const int* __restrict__ boff,
                                                int* __restrict__ rowptr){
    __shared__ int s[256];
    int t = threadIdx.x;
    int i = blockIdx.x*256 + t;
    int v = (i < NN) ? deg[i] : 0;
    s[t] = v;
    __syncthreads();
    for (int off = 1; off < 256; off <<= 1){
        int u = (t >= off) ? s[t - off] : 0;
        __syncthreads();
        s[t] += u;
        __syncthreads();
    }
    if (i < NN) rowptr[i] = boff[blockIdx.x] + s[t] - v;
}

// fill CSR: per edge, packed {src, norm}
__global__ void k_fill(const int* __restrict__ row, const int* __restrict__ col,
                       const float* __restrict__ dis, const int* __restrict__ rowptr,
                       int* __restrict__ cursor, int2* __restrict__ edge){
    int e = blockIdx.x * blockDim.x + threadIdx.x;
    if (e >= NE) return;
    int r = row[e], c = col[e];
    int idx = rowptr[c] + atomicAdd(&cursor[c], 1);
    edge[idx] = make_int2(r, __float_as_int(dis[r] * dis[c]));
}

// ======== layer 1: gather 3-channel, thread per node ========
__global__ void k_gather3(const float* __restrict__ x, const int* __restrict__ rowptr,
                          const int2* __restrict__ edge, float* __restrict__ agg){
    int n = blockIdx.x * blockDim.x + threadIdx.x;
    if (n >= NN) return;
    int j0 = rowptr[n], j1 = rowptr[n + 1];
    float a0 = 0.f, a1 = 0.f, a2 = 0.f;
    for (int j = j0; j < j1; ++j){
        int2 e = edge[j];
        int r = e.x; float w = __int_as_float(e.y);
        a0 = fmaf(x[r*3+0], w, a0);
        a1 = fmaf(x[r*3+1], w, a1);
        a2 = fmaf(x[r*3+2], w, a2);
    }
    agg[n*3+0] = a0; agg[n*3+1] = a1; agg[n*3+2] = a2;
}

// ---- layer 1 dense + fused pool: channel per thread, 128 nodes per block ----
__global__ __launch_bounds__(128) void k_dense3p(const float* __restrict__ agg, const float* __restrict__ W,
                          const float* __restrict__ b, float* __restrict__ h, float* __restrict__ part){
    int c = threadIdx.x;
    int n0 = blockIdx.x * 128;
    int n1 = min(n0 + 128, NN);
    float w0 = W[c*3+0], w1 = W[c*3+1], w2 = W[c*3+2], bb = b[c];
    float s = 0.f, m = -3.4e38f;
    for (int n = n0; n < n1; ++n){
        float v = fmaf(agg[n*3+0], w0, fmaf(agg[n*3+1], w1, fmaf(agg[n*3+2], w2, bb)));
        v = elu_f(v);
        h[(size_t)n*128 + c] = v;
        s += v; m = fmaxf(m, v);
    }
    part[blockIdx.x*128 + c] = s;
    part[PMAX + blockIdx.x*128 + c] = m;
}

// ======== 128-channel gather: agg[n] = att * sum_j h[src[j]] * nrm[j] ========
__global__ __launch_bounds__(256) void k_gather128(const float* __restrict__ h,
                              const int* __restrict__ rowptr, const int2* __restrict__ edge,
                              const float* __restrict__ att, float* __restrict__ agg){
    int t = blockIdx.x * blockDim.x + threadIdx.x;
    int n = t >> 5, l = t & 31;
    if (n >= NN) return;
    int j0 = rowptr[n], j1 = rowptr[n + 1];
    float4 acc = {0.f, 0.f, 0.f, 0.f};
    int j = j0;
    for (; j + 3 < j1; j += 4){
        int2 e0 = edge[j], e1 = edge[j+1], e2 = edge[j+2], e3 = edge[j+3];
        float4 v0 = ((const float4*)(h + (size_t)e0.x*128))[l];
        float4 v1 = ((const float4*)(h + (size_t)e1.x*128))[l];
        float4 v2 = ((const float4*)(h + (size_t)e2.x*128))[l];
        float4 v3 = ((const float4*)(h + (size_t)e3.x*128))[l];
        fma4(acc, __int_as_float(e0.y), v0);
        fma4(acc, __int_as_float(e1.y), v1);
        fma4(acc, __int_as_float(e2.y), v2);
        fma4(acc, __int_as_float(e3.y), v3);
    }
    for (; j < j1; ++j){
        int2 e0 = edge[j];
        float4 v0 = ((const float4*)(h + (size_t)e0.x*128))[l];
        fma4(acc, __int_as_float(e0.y), v0);
    }
    float4 a = ((const float4*)att)[l];
    acc.x *= a.x; acc.y *= a.y; acc.z *= a.z; acc.w *= a.w;
    ((float4*)(agg + (size_t)n*128))[l] = acc;
}

// ---- pool partial pre-reduction: nblk rows -> NRED rows ----
__global__ __launch_bounds__(256) void k_attn_pre(const float* __restrict__ part, int nblk,
                                                  float* __restrict__ part2){
    __shared__ float sS[2][128], sM[2][128];
    int c = threadIdx.x & 127, g = threadIdx.x >> 7;   // 2 groups
    float s = 0.f, m = -3.4e38f;
    for (int b = blockIdx.x*2 + g; b < nblk; b += NRED*2){
        s += part[b*128 + c];
        m = fmaxf(m, part[PMAX + b*128 + c]);
    }
    sS[g][c] = s; sM[g][c] = m;
    __syncthreads();
    if (g == 0){
        part2[blockIdx.x*128 + c] = sS[0][c] + sS[1][c];
        part2[NRED*128 + blockIdx.x*128 + c] = fmaxf(sM[0][c], sM[1][c]);
    }
}

// ---- channel attention MLP: att = sigmoid(mlp(avg)+mlp(max)) ----
__global__ __launch_bounds__(512) void k_attn(const float* __restrict__ part2,
                       const float* __restrict__ w1, const float* __restrict__ w2,
                       float* __restrict__ att){
    __shared__ float sAll[4][128], mAll[4][128];
    __shared__ float avg[128], mx[128], ha[8], hm[8];
    int c = threadIdx.x & 127, g = threadIdx.x >> 7;
    float s = 0.f, m = -3.4e38f;
    #pragma unroll
    for (int b = 0; b < NRED/4; ++b){
        int r = b*4 + g;
        s += part2[r*128 + c];
        m = fmaxf(m, part2[NRED*128 + r*128 + c]);
    }
    sAll[g][c] = s; mAll[g][c] = m;
    __syncthreads();
    if (g == 0){
        s = sAll[0][c] + sAll[1][c] + sAll[2][c] + sAll[3][c];
        m = fmaxf(fmaxf(mAll[0][c], mAll[1][c]), fmaxf(mAll[2][c], mAll[3][c]));
        avg[c] = s / (float)NN;
        mx[c] = m;
    }
    __syncthreads();
    if (threadIdx.x < 8){
        int cc = threadIdx.x;
        float sa = 0.f, sm = 0.f;
        for (int k = 0; k < 128; ++k){
            float w = w1[cc*128 + k];
            sa += avg[k]*w; sm += mx[k]*w;
        }
        ha[cc] = fmaxf(sa, 0.f); hm[cc] = fmaxf(sm, 0.f);
    }
    __syncthreads();
    if (threadIdx.x < 128){
        float oa = 0.f, om = 0.f;
        for (int j = 0; j < 8; ++j){
            float w = w2[c*8 + j];
            oa += ha[j]*w; om += hm[j]*w;
        }
        att[c] = 1.f / (1.f + __expf(-(oa + om)));
    }
}

// ---- dense: out = ELU(A @ W^T + b) + fused pool partials ----
__global__ __launch_bounds__(256) void k_gemm128(const float* __restrict__ A, const float* __restrict__ W,
                         const float* __restrict__ b, float* __restrict__ out, float* __restrict__ part){
    __shared__ float4 WtV[128*32];   // swizzled transposed W
    __shared__ float At[GN*128];
    int tid = threadIdx.x;
    float* Wt = (float*)WtV;
    for (int i = tid; i < 128*128; i += 256){
        int j = i >> 7, cc = i & 127;
        int slot = (cc*32 + (((j>>2) + cc) & 31))*4 + (j&3);
        Wt[slot] = W[i];
    }
    int n0 = blockIdx.x * GN;
    for (int i = tid; i < GN*128; i += 256){
        int n = n0 + (i >> 7);
        At[i] = (n < NN) ? A[(size_t)n*128 + (i & 127)] : 0.f;
    }
    __syncthreads();
    int jg = tid & 31, ng = tid >> 5;   // channels 4jg..+3, nodes ng*4..+3
    float4 bv = ((const float4*)b)[jg];
    float4 acc0 = bv, acc1 = bv, acc2 = bv, acc3 = bv;
    const float4* A0 = (const float4*)(At + (ng*4+0)*128);
    const float4* A1 = (const float4*)(At + (ng*4+1)*128);
    const float4* A2 = (const float4*)(At + (ng*4+2)*128);
    const float4* A3 = (const float4*)(At + (ng*4+3)*128);
    #pragma unroll 4
    for (int c4 = 0; c4 < 32; ++c4){
        int cb = c4*4;
        float4 w0 = WtV[(cb+0)*32 + ((jg + cb+0)&31)];
        float4 w1 = WtV[(cb+1)*32 + ((jg + cb+1)&31)];
        float4 w2 = WtV[(cb+2)*32 + ((jg + cb+2)&31)];
        float4 w3 = WtV[(cb+3)*32 + ((jg + cb+3)&31)];
        float4 a;
        a = A0[c4]; fma4(acc0,a.x,w0); fma4(acc0,a.y,w1); fma4(acc0,a.z,w2); fma4(acc0,a.w,w3);
        a = A1[c4]; fma4(acc1,a.x,w0); fma4(acc1,a.y,w1); fma4(acc1,a.z,w2); fma4(acc1,a.w,w3);
        a = A2[c4]; fma4(acc2,a.x,w0); fma4(acc2,a.y,w1); fma4(acc2,a.z,w2); fma4(acc2,a.w,w3);
        a = A3[c4]; fma4(acc3,a.x,w0); fma4(acc3,a.y,w1); fma4(acc3,a.z,w2); fma4(acc3,a.w,w3);
    }
    float4 accs[4] = {acc0, acc1, acc2, acc3};
    float4 s4 = {0.f,0.f,0.f,0.f};
    float4 m4 = {-3.4e38f,-3.4e38f,-3.4e38f,-3.4e38f};
    #pragma unroll
    for (int k = 0; k < 4; ++k){
        int n = n0 + ng*4 + k;
        float4 v = accs[k];
        v.x = elu_f(v.x); v.y = elu_f(v.y); v.z = elu_f(v.z); v.w = elu_f(v.w);
        if (n < NN){
            ((float4*)(out + (size_t)n*128))[jg] = v;
            add4(s4, v); max4(m4, v);
        }
    }
    // pool reduce across ng groups (reuse At as scratch)
    __syncthreads();
    float4* reds = (float4*)At;          // [8][32]
    float4* redm = reds + 256;           // [8][32]
    reds[ng*32 + jg] = s4;
    redm[ng*32 + jg] = m4;
    __syncthreads();
    if (tid < 32){
        float4 S = {0.f,0.f,0.f,0.f};
        float4 M = {-3.4e38f,-3.4e38f,-3.4e38f,-3.4e38f};
        #pragma unroll
        for (int g = 0; g < 8; ++g){ add4(S, reds[g*32 + tid]); max4(M, redm[g*32 + tid]); }
        ((float4*)(part + blockIdx.x*128))[tid] = S;
        ((float4*)(part + PMAX + blockIdx.x*128))[tid] = M;
    }
}

// ---- output head: out[n,k] = sum_c h[n,c]*att[c]*Wout[k,c] + bout[k] ----
__global__ void k_out(const float* __restrict__ h, const float* __restrict__ att,
                      const float* __restrict__ Wo, const float* __restrict__ bo,
                      float* __restrict__ out){
    int t = blockIdx.x * blockDim.x + threadIdx.x;
    if (t >= NN*3) return;
    int n = t / 3, k = t - n*3;
    const float4* hv = (const float4*)(h + (size_t)n*128);
    const float4* av = (const float4*)att;
    const float4* wv = (const float4*)(Wo + k*128);
    float acc = bo[k];
    #pragma unroll 8
    for (int i = 0; i < 32; ++i){
        float4 hh = hv[i], aa = av[i], ww = wv[i];
        acc += hh.x*aa.x*ww.x + hh.y*aa.y*ww.y + hh.z*aa.z*ww.z + hh.w*aa.w*ww.w;
    }
    out[t] = acc;
}

extern "C" void kernel_launch(void* const* d_in, const int* in_sizes, int n_in,
                              void* d_out, int out_size, void* d_ws, size_t ws_size,
                              hipStream_t stream) {
    const float* x    = (const float*)d_in[0];
    const int*   ei   = (const int*)d_in[1];
    const int*   row  = ei;
    const int*   col  = ei + NE;
    const float* dis  = (const float*)d_in[2];
    const float* W1   = (const float*)d_in[3];
    const float* b1   = (const float*)d_in[4];
    const float* W2   = (const float*)d_in[5];
    const float* b2   = (const float*)d_in[6];
    const float* W3   = (const float*)d_in[7];
    const float* b3   = (const float*)d_in[8];
    const float* ca1w1= (const float*)d_in[9];
    const float* ca1w2= (const float*)d_in[10];
    const float* ca2w1= (const float*)d_in[11];
    const float* ca2w2= (const float*)d_in[12];
    const float* ca3w1= (const float*)d_in[13];
    const float* ca3w2= (const float*)d_in[14];
    const float* Wout = (const float*)d_in[15];
    const float* bout = (const float*)d_in[16];
    float* out = (float*)d_out;

    float* bufA = (float*)d_ws;                         // [N,128]
    float* bufB = bufA + (size_t)NN*128;                // [N,128]; first 150K also agg3
    float* part = bufB + (size_t)NN*128;                // 2*NBGEMM*128
    float* part2 = part + (size_t)2*PMAX;               // 2*NRED*128
    float* att1 = part2 + 2*NRED*128;
    float* att2 = att1 + 128;
    float* att3 = att2 + 128;
    int2*  edge = (int2*)(att3 + 128);                  // [NE] {src, norm}
    int*   rowptr = (int*)(edge + NE);                  // [NN+1]
    int*   deg  = rowptr + NN + 1;                      // [NN]
    int*   cursor = deg + NN;                           // [NN]
    int*   bsum = cursor + NN;                          // [NB1]
    int*   boff = bsum + NB1;                           // [NB1]

    const int gath_blocks = (NN * 32 + 255) / 256;

    // ---- CSR build (reused by all 3 layers) ----
    hipMemsetAsync(deg, 0, (size_t)NN * 2 * sizeof(int), stream);   // deg + cursor
    k_hist<<<(NE+255)/256, 256, 0, stream>>>(col, deg);
    k_psum<<<NB1, 256, 0, stream>>>(deg, bsum);
    k_pscan<<<1, 256, 0, stream>>>(bsum, boff, rowptr);
    k_rowptr<<<NB1, 256, 0, stream>>>(deg, boff, rowptr);
    k_fill<<<(NE+255)/256, 256, 0, stream>>>(row, col, dis, rowptr, cursor, edge);

    // ---- layer 1 ----
    k_gather3<<<(NN+255)/256, 256, 0, stream>>>(x, rowptr, edge, bufB);
    k_dense3p<<<NBD3, 128, 0, stream>>>(bufB, W1, b1, bufA, part);
    k_attn_pre<<<NRED, 256, 0, stream>>>(part, NBD3, part2);
    k_attn<<<1, 512, 0, stream>>>(part2, ca1w1, ca1w2, att1);

    // ---- layer 2 ----
    k_gather128<<<gath_blocks, 256, 0, stream>>>(bufA, rowptr, edge, att1, bufB);
    k_gemm128<<<NBGEMM, 256, 0, stream>>>(bufB, W2, b2, bufA, part);
    k_attn_pre<<<NRED, 256, 0, stream>>>(part, NBGEMM, part2);
    k_attn<<<1, 512, 0, stream>>>(part2, ca2w1, ca2w2, att2);

    // ---- layer 3 ----
    k_gather128<<<gath_blocks, 256, 0, stream>>>(bufA, rowptr, edge, att2, bufB);
    k_gemm128<<<NBGEMM, 256, 0, stream>>>(bufB, W3, b3, bufA, part);
    k_attn_pre<<<NRED, 256, 0, stream>>>(part, NBGEMM, part2);
    k_attn<<<1, 512, 0, stream>>>(part2, ca3w1, ca3w2, att3);

    // ---- output head (att3 folded in) ----
    k_out<<<(NN*3 + 255)/256, 256, 0, stream>>>(bufA, att3, Wout, bout, out);
}

// Round 5
// 326.401 us; speedup vs baseline: 1.9233x; 1.2217x over previous
//
#include <hip/hip_runtime.h>

#define NN 50000
#define NE 800000
#define NPAD 50176                  // NN padded to multiple of 64
#define NB1 196                     // ceil(NN/256) scan blocks
#define NBD3 391                    // ceil(NN/128) dense3 blocks
#define NBG 782                     // ceil(NN/64) mfma-gemm blocks
#define PMAX (NBG*128)              // offset of max-partials in part buffer
#define NRED 64                     // reduced partial rows after k_attn_pre

typedef __attribute__((ext_vector_type(8))) short bf16x8;
typedef __attribute__((ext_vector_type(4))) float f32x4;

__device__ __forceinline__ float elu_f(float x){ return x > 0.f ? x : __expf(x) - 1.f; }

__device__ __forceinline__ ushort f2bf(float f){
    unsigned u = __float_as_uint(f);
    unsigned r = (u + 0x7FFFu + ((u >> 16) & 1u)) >> 16;
    return (ushort)r;
}

__device__ __forceinline__ void fma4(float4& a, float s, const float4& w){
    a.x += s*w.x; a.y += s*w.y; a.z += s*w.z; a.w += s*w.w;
}

// ======== CSR build (by destination col) ========
__global__ void k_hist(const int* __restrict__ col, int* __restrict__ deg){
    int e = blockIdx.x * blockDim.x + threadIdx.x;
    if (e >= NE) return;
    atomicAdd(&deg[col[e]], 1);
}

__global__ __launch_bounds__(256) void k_psum(const int* __restrict__ deg, int* __restrict__ bsum){
    __shared__ int red[256];
    int i = blockIdx.x*256 + threadIdx.x;
    red[threadIdx.x] = (i < NN) ? deg[i] : 0;
    __syncthreads();
    for (int off = 128; off > 0; off >>= 1){
        if (threadIdx.x < off) red[threadIdx.x] += red[threadIdx.x + off];
        __syncthreads();
    }
    if (threadIdx.x == 0) bsum[blockIdx.x] = red[0];
}

__global__ __launch_bounds__(256) void k_pscan(const int* __restrict__ bsum, int* __restrict__ boff,
                                               int* __restrict__ rowptr){
    __shared__ int s[256];
    int t = threadIdx.x;
    int v = (t < NB1) ? bsum[t] : 0;
    s[t] = v;
    __syncthreads();
    for (int off = 1; off < 256; off <<= 1){
        int u = (t >= off) ? s[t - off] : 0;
        __syncthreads();
        s[t] += u;
        __syncthreads();
    }
    if (t < NB1) boff[t] = s[t] - v;
    if (t == 255) rowptr[NN] = s[255];
}

__global__ __launch_bounds__(256) void k_rowptr(const int* __restrict__ deg, const int* __restrict__ boff,
                                                int* __restrict__ rowptr){
    __shared__ int s[256];
    int t = threadIdx.x;
    int i = blockIdx.x*256 + t;
    int v = (i < NN) ? deg[i] : 0;
    s[t] = v;
    __syncthreads();
    for (int off = 1; off < 256; off <<= 1){
        int u = (t >= off) ? s[t - off] : 0;
        __syncthreads();
        s[t] += u;
        __syncthreads();
    }
    if (i < NN) rowptr[i] = boff[blockIdx.x] + s[t] - v;
}

__global__ void k_fill(const int* __restrict__ row, const int* __restrict__ col,
                       const float* __restrict__ dis, const int* __restrict__ rowptr,
                       int* __restrict__ cursor, int2* __restrict__ edge){
    int e = blockIdx.x * blockDim.x + threadIdx.x;
    if (e >= NE) return;
    int r = row[e], c = col[e];
    int idx = rowptr[c] + atomicAdd(&cursor[c], 1);
    edge[idx] = make_int2(r, __float_as_int(dis[r] * dis[c]));
}

// ---- convert W2,W3 to bf16 ----
__global__ void k_convW(const float* __restrict__ W2, const float* __restrict__ W3,
                        ushort* __restrict__ Wb2, ushort* __restrict__ Wb3){
    int i = blockIdx.x*256 + threadIdx.x;
    if (i < 16384){ Wb2[i] = f2bf(W2[i]); Wb3[i] = f2bf(W3[i]); }
}

// ======== layer 1: gather 3-channel, thread per node ========
__global__ void k_gather3(const float* __restrict__ x, const int* __restrict__ rowptr,
                          const int2* __restrict__ edge, float* __restrict__ agg){
    int n = blockIdx.x * blockDim.x + threadIdx.x;
    if (n >= NN) return;
    int j0 = rowptr[n], j1 = rowptr[n + 1];
    float a0 = 0.f, a1 = 0.f, a2 = 0.f;
    for (int j = j0; j < j1; ++j){
        int2 e = edge[j];
        int r = e.x; float w = __int_as_float(e.y);
        a0 = fmaf(x[r*3+0], w, a0);
        a1 = fmaf(x[r*3+1], w, a1);
        a2 = fmaf(x[r*3+2], w, a2);
    }
    agg[n*3+0] = a0; agg[n*3+1] = a1; agg[n*3+2] = a2;
}

// ---- layer 1 dense + fused pool ----
__global__ __launch_bounds__(128) void k_dense3p(const float* __restrict__ agg, const float* __restrict__ W,
                          const float* __restrict__ b, float* __restrict__ h, float* __restrict__ part){
    int c = threadIdx.x;
    int n0 = blockIdx.x * 128;
    int n1 = min(n0 + 128, NN);
    float w0 = W[c*3+0], w1 = W[c*3+1], w2 = W[c*3+2], bb = b[c];
    float s = 0.f, m = -3.4e38f;
    for (int n = n0; n < n1; ++n){
        float v = fmaf(agg[n*3+0], w0, fmaf(agg[n*3+1], w1, fmaf(agg[n*3+2], w2, bb)));
        v = elu_f(v);
        h[(size_t)n*128 + c] = v;
        s += v; m = fmaxf(m, v);
    }
    part[blockIdx.x*128 + c] = s;
    part[PMAX + blockIdx.x*128 + c] = m;
}

// ======== 128-channel gather -> bf16 agg ========
__global__ __launch_bounds__(256) void k_gather128(const float* __restrict__ h,
                              const int* __restrict__ rowptr, const int2* __restrict__ edge,
                              const float* __restrict__ att, ushort* __restrict__ aggB){
    int t = blockIdx.x * blockDim.x + threadIdx.x;
    int n = t >> 5, l = t & 31;
    if (n >= NN) return;
    int j0 = rowptr[n], j1 = rowptr[n + 1];
    float4 acc = {0.f, 0.f, 0.f, 0.f};
    int j = j0;
    for (; j + 3 < j1; j += 4){
        int2 e0 = edge[j], e1 = edge[j+1], e2 = edge[j+2], e3 = edge[j+3];
        float4 v0 = ((const float4*)(h + (size_t)e0.x*128))[l];
        float4 v1 = ((const float4*)(h + (size_t)e1.x*128))[l];
        float4 v2 = ((const float4*)(h + (size_t)e2.x*128))[l];
        float4 v3 = ((const float4*)(h + (size_t)e3.x*128))[l];
        fma4(acc, __int_as_float(e0.y), v0);
        fma4(acc, __int_as_float(e1.y), v1);
        fma4(acc, __int_as_float(e2.y), v2);
        fma4(acc, __int_as_float(e3.y), v3);
    }
    for (; j < j1; ++j){
        int2 e0 = edge[j];
        float4 v0 = ((const float4*)(h + (size_t)e0.x*128))[l];
        fma4(acc, __int_as_float(e0.y), v0);
    }
    float4 a = ((const float4*)att)[l];
    ushort4 o;
    o.x = f2bf(acc.x * a.x);
    o.y = f2bf(acc.y * a.y);
    o.z = f2bf(acc.z * a.z);
    o.w = f2bf(acc.w * a.w);
    ((ushort4*)(aggB + (size_t)n*128))[l] = o;
}

// ---- pool partial pre-reduction ----
__global__ __launch_bounds__(256) void k_attn_pre(const float* __restrict__ part, int nblk,
                                                  float* __restrict__ part2){
    __shared__ float sS[2][128], sM[2][128];
    int c = threadIdx.x & 127, g = threadIdx.x >> 7;
    float s = 0.f, m = -3.4e38f;
    for (int b = blockIdx.x*2 + g; b < nblk; b += NRED*2){
        s += part[b*128 + c];
        m = fmaxf(m, part[PMAX + b*128 + c]);
    }
    sS[g][c] = s; sM[g][c] = m;
    __syncthreads();
    if (g == 0){
        part2[blockIdx.x*128 + c] = sS[0][c] + sS[1][c];
        part2[NRED*128 + blockIdx.x*128 + c] = fmaxf(sM[0][c], sM[1][c]);
    }
}

// ---- channel attention MLP ----
__global__ __launch_bounds__(512) void k_attn(const float* __restrict__ part2,
                       const float* __restrict__ w1, const float* __restrict__ w2,
                       float* __restrict__ att){
    __shared__ float sAll[4][128], mAll[4][128];
    __shared__ float avg[128], mx[128], ha[8], hm[8];
    int c = threadIdx.x & 127, g = threadIdx.x >> 7;
    float s = 0.f, m = -3.4e38f;
    #pragma unroll
    for (int b = 0; b < NRED/4; ++b){
        int r = b*4 + g;
        s += part2[r*128 + c];
        m = fmaxf(m, part2[NRED*128 + r*128 + c]);
    }
    sAll[g][c] = s; mAll[g][c] = m;
    __syncthreads();
    if (g == 0){
        s = sAll[0][c] + sAll[1][c] + sAll[2][c] + sAll[3][c];
        m = fmaxf(fmaxf(mAll[0][c], mAll[1][c]), fmaxf(mAll[2][c], mAll[3][c]));
        avg[c] = s / (float)NN;
        mx[c] = m;
    }
    __syncthreads();
    if (threadIdx.x < 8){
        int cc = threadIdx.x;
        float sa = 0.f, sm = 0.f;
        for (int k = 0; k < 128; ++k){
            float w = w1[cc*128 + k];
            sa += avg[k]*w; sm += mx[k]*w;
        }
        ha[cc] = fmaxf(sa, 0.f); hm[cc] = fmaxf(sm, 0.f);
    }
    __syncthreads();
    if (threadIdx.x < 128){
        float oa = 0.f, om = 0.f;
        for (int j = 0; j < 8; ++j){
            float w = w2[c*8 + j];
            oa += ha[j]*w; om += hm[j]*w;
        }
        att[c] = 1.f / (1.f + __expf(-(oa + om)));
    }
}

// ======== MFMA GEMM: h = ELU(aggB @ Wb^T + b) + fused pool ========
// block = 256 thr = 4 waves; wave = 16 nodes x 128 cols; no LDS tile.
// A-frag: row = lane&15, k = (lane>>4)*8+e  -> 16B contiguous from aggB row
// B-frag: col = lane&15, k = (lane>>4)*8+e  -> B[k][j]=W[j][k]: 16B from Wb row
// D:      col = lane&15, row = (lane>>4)*4+reg   (m89-verified mapping)
__global__ __launch_bounds__(256) void k_gemm_mfma(const ushort* __restrict__ aggB,
                        const ushort* __restrict__ Wb, const float* __restrict__ b,
                        float* __restrict__ h, float* __restrict__ part){
    __shared__ float poolS[4][128], poolM[4][128];
    int tid = threadIdx.x;
    int wave = tid >> 6, l = tid & 63;
    int lr = l & 15, lk = l >> 4;
    int n0 = blockIdx.x * 64 + wave * 16;

    bf16x8 a[4];
    const ushort* arow = aggB + (size_t)(n0 + lr) * 128 + lk * 8;
    #pragma unroll
    for (int kb = 0; kb < 4; ++kb)
        a[kb] = *(const bf16x8*)(arow + kb * 32);

    float s_part[8], m_part[8];
    const ushort* wbase = Wb + (size_t)lr * 128 + lk * 8;
    #pragma unroll
    for (int t = 0; t < 8; ++t){
        int j0 = t * 16;
        float bias = b[j0 + lr];
        f32x4 acc = {bias, bias, bias, bias};
        const ushort* wrow = wbase + (size_t)j0 * 128;
        #pragma unroll
        for (int kb = 0; kb < 4; ++kb){
            bf16x8 bf = *(const bf16x8*)(wrow + kb * 32);
            acc = __builtin_amdgcn_mfma_f32_16x16x32_bf16(a[kb], bf, acc, 0, 0, 0);
        }
        float s = 0.f, m = -3.4e38f;
        #pragma unroll
        for (int r = 0; r < 4; ++r){
            int n = n0 + lk * 4 + r;
            float v = elu_f(acc[r]);
            if (n < NN){
                h[(size_t)n * 128 + j0 + lr] = v;
                s += v; m = fmaxf(m, v);
            }
        }
        s += __shfl_xor(s, 16); s += __shfl_xor(s, 32);
        m = fmaxf(m, __shfl_xor(m, 16)); m = fmaxf(m, __shfl_xor(m, 32));
        s_part[t] = s; m_part[t] = m;
    }
    if (lk == 0){
        #pragma unroll
        for (int t = 0; t < 8; ++t){
            poolS[wave][t * 16 + lr] = s_part[t];
            poolM[wave][t * 16 + lr] = m_part[t];
        }
    }
    __syncthreads();
    if (tid < 128){
        float S = poolS[0][tid] + poolS[1][tid] + poolS[2][tid] + poolS[3][tid];
        float M = fmaxf(fmaxf(poolM[0][tid], poolM[1][tid]), fmaxf(poolM[2][tid], poolM[3][tid]));
        part[blockIdx.x * 128 + tid] = S;
        part[PMAX + blockIdx.x * 128 + tid] = M;
    }
}

// ---- output head ----
__global__ void k_out(const float* __restrict__ h, const float* __restrict__ att,
                      const float* __restrict__ Wo, const float* __restrict__ bo,
                      float* __restrict__ out){
    int t = blockIdx.x * blockDim.x + threadIdx.x;
    if (t >= NN*3) return;
    int n = t / 3, k = t - n*3;
    const float4* hv = (const float4*)(h + (size_t)n*128);
    const float4* av = (const float4*)att;
    const float4* wv = (const float4*)(Wo + k*128);
    float acc = bo[k];
    #pragma unroll 8
    for (int i = 0; i < 32; ++i){
        float4 hh = hv[i], aa = av[i], ww = wv[i];
        acc += hh.x*aa.x*ww.x + hh.y*aa.y*ww.y + hh.z*aa.z*ww.z + hh.w*aa.w*ww.w;
    }
    out[t] = acc;
}

extern "C" void kernel_launch(void* const* d_in, const int* in_sizes, int n_in,
                              void* d_out, int out_size, void* d_ws, size_t ws_size,
                              hipStream_t stream) {
    const float* x    = (const float*)d_in[0];
    const int*   ei   = (const int*)d_in[1];
    const int*   row  = ei;
    const int*   col  = ei + NE;
    const float* dis  = (const float*)d_in[2];
    const float* W1   = (const float*)d_in[3];
    const float* b1   = (const float*)d_in[4];
    const float* W2   = (const float*)d_in[5];
    const float* b2   = (const float*)d_in[6];
    const float* W3   = (const float*)d_in[7];
    const float* b3   = (const float*)d_in[8];
    const float* ca1w1= (const float*)d_in[9];
    const float* ca1w2= (const float*)d_in[10];
    const float* ca2w1= (const float*)d_in[11];
    const float* ca2w2= (const float*)d_in[12];
    const float* ca3w1= (const float*)d_in[13];
    const float* ca3w2= (const float*)d_in[14];
    const float* Wout = (const float*)d_in[15];
    const float* bout = (const float*)d_in[16];
    float* out = (float*)d_out;

    float*  bufA  = (float*)d_ws;                         // [NN,128] f32 h
    ushort* aggB  = (ushort*)(bufA + (size_t)NN*128);     // [NPAD,128] bf16
    float*  agg3  = (float*)(aggB + (size_t)NPAD*128);    // [NN,3]
    float*  part  = agg3 + (size_t)NN*3;                  // 2*PMAX
    float*  part2 = part + (size_t)2*PMAX;                // 2*NRED*128
    float*  att1  = part2 + 2*NRED*128;
    float*  att2  = att1 + 128;
    float*  att3  = att2 + 128;
    ushort* Wb2   = (ushort*)(att3 + 128);                // [128,128] bf16
    ushort* Wb3   = Wb2 + 16384;
    int2*   edge  = (int2*)(Wb3 + 16384);                 // [NE]
    int*    rowptr= (int*)(edge + NE);                    // [NN+1]
    int*    deg   = rowptr + NN + 1;
    int*    cursor= deg + NN;
    int*    bsum  = cursor + NN;
    int*    boff  = bsum + NB1;

    const int gath_blocks = (NN * 32 + 255) / 256;

    // ---- CSR build + weight conversion ----
    hipMemsetAsync(deg, 0, (size_t)NN * 2 * sizeof(int), stream);
    k_hist<<<(NE+255)/256, 256, 0, stream>>>(col, deg);
    k_convW<<<64, 256, 0, stream>>>(W2, W3, Wb2, Wb3);
    k_psum<<<NB1, 256, 0, stream>>>(deg, bsum);
    k_pscan<<<1, 256, 0, stream>>>(bsum, boff, rowptr);
    k_rowptr<<<NB1, 256, 0, stream>>>(deg, boff, rowptr);
    k_fill<<<(NE+255)/256, 256, 0, stream>>>(row, col, dis, rowptr, cursor, edge);

    // ---- layer 1 ----
    k_gather3<<<(NN+255)/256, 256, 0, stream>>>(x, rowptr, edge, agg3);
    k_dense3p<<<NBD3, 128, 0, stream>>>(agg3, W1, b1, bufA, part);
    k_attn_pre<<<NRED, 256, 0, stream>>>(part, NBD3, part2);
    k_attn<<<1, 512, 0, stream>>>(part2, ca1w1, ca1w2, att1);

    // ---- layer 2 ----
    k_gather128<<<gath_blocks, 256, 0, stream>>>(bufA, rowptr, edge, att1, aggB);
    k_gemm_mfma<<<NBG, 256, 0, stream>>>(aggB, Wb2, b2, bufA, part);
    k_attn_pre<<<NRED, 256, 0, stream>>>(part, NBG, part2);
    k_attn<<<1, 512, 0, stream>>>(part2, ca2w1, ca2w2, att2);

    // ---- layer 3 ----
    k_gather128<<<gath_blocks, 256, 0, stream>>>(bufA, rowptr, edge, att2, aggB);
    k_gemm_mfma<<<NBG, 256, 0, stream>>>(aggB, Wb3, b3, bufA, part);
    k_attn_pre<<<NRED, 256, 0, stream>>>(part, NBG, part2);
    k_attn<<<1, 512, 0, stream>>>(part2, ca3w1, ca3w2, att3);

    // ---- output head (att3 folded in) ----
    k_out<<<(NN*3 + 255)/256, 256, 0, stream>>>(bufA, att3, Wout, bout, out);
}

// Round 6
// 273.009 us; speedup vs baseline: 2.2994x; 1.1956x over previous
//
#include <hip/hip_runtime.h>

#define NN 50000
#define NE 800000
#define NPAD 50176                  // NN padded to multiple of 64
#define NB1 196                     // ceil(NN/256) scan blocks
#define NBD3 391                    // ceil(NN/128) dense3 blocks
#define NBG 782                     // ceil(NN/64) mfma-gemm blocks
#define PMAX (NBG*128)              // offset of max-partials in part buffer
#define NRED 64                     // reduced partial rows after k_attn_pre

typedef __attribute__((ext_vector_type(8))) short bf16x8;
typedef __attribute__((ext_vector_type(4))) float f32x4;

__device__ __forceinline__ float elu_f(float x){ return x > 0.f ? x : __expf(x) - 1.f; }

__device__ __forceinline__ ushort f2bf(float f){
    unsigned u = __float_as_uint(f);
    unsigned r = (u + 0x7FFFu + ((u >> 16) & 1u)) >> 16;
    return (ushort)r;
}
__device__ __forceinline__ float bf2f(short u){
    return __uint_as_float(((unsigned)(unsigned short)u) << 16);
}

// ======== CSR build (by destination col) ========
__global__ void k_hist(const int* __restrict__ col, int* __restrict__ deg){
    int e = blockIdx.x * blockDim.x + threadIdx.x;
    if (e >= NE) return;
    atomicAdd(&deg[col[e]], 1);
}

__global__ __launch_bounds__(256) void k_psum(const int* __restrict__ deg, int* __restrict__ bsum){
    __shared__ int red[256];
    int i = blockIdx.x*256 + threadIdx.x;
    red[threadIdx.x] = (i < NN) ? deg[i] : 0;
    __syncthreads();
    for (int off = 128; off > 0; off >>= 1){
        if (threadIdx.x < off) red[threadIdx.x] += red[threadIdx.x + off];
        __syncthreads();
    }
    if (threadIdx.x == 0) bsum[blockIdx.x] = red[0];
}

__global__ __launch_bounds__(256) void k_pscan(const int* __restrict__ bsum, int* __restrict__ boff,
                                               int* __restrict__ rowptr){
    __shared__ int s[256];
    int t = threadIdx.x;
    int v = (t < NB1) ? bsum[t] : 0;
    s[t] = v;
    __syncthreads();
    for (int off = 1; off < 256; off <<= 1){
        int u = (t >= off) ? s[t - off] : 0;
        __syncthreads();
        s[t] += u;
        __syncthreads();
    }
    if (t < NB1) boff[t] = s[t] - v;
    if (t == 255) rowptr[NN] = s[255];
}

__global__ __launch_bounds__(256) void k_rowptr(const int* __restrict__ deg, const int* __restrict__ boff,
                                                int* __restrict__ rowptr){
    __shared__ int s[256];
    int t = threadIdx.x;
    int i = blockIdx.x*256 + t;
    int v = (i < NN) ? deg[i] : 0;
    s[t] = v;
    __syncthreads();
    for (int off = 1; off < 256; off <<= 1){
        int u = (t >= off) ? s[t - off] : 0;
        __syncthreads();
        s[t] += u;
        __syncthreads();
    }
    if (i < NN) rowptr[i] = boff[blockIdx.x] + s[t] - v;
}

__global__ void k_fill(const int* __restrict__ row, const int* __restrict__ col,
                       const float* __restrict__ dis, const int* __restrict__ rowptr,
                       int* __restrict__ cursor, int2* __restrict__ edge){
    int e = blockIdx.x * blockDim.x + threadIdx.x;
    if (e >= NE) return;
    int r = row[e], c = col[e];
    int idx = rowptr[c] + atomicAdd(&cursor[c], 1);
    edge[idx] = make_int2(r, __float_as_int(dis[r] * dis[c]));
}

// ---- convert W2,W3 to bf16 ----
__global__ void k_convW(const float* __restrict__ W2, const float* __restrict__ W3,
                        ushort* __restrict__ Wb2, ushort* __restrict__ Wb3){
    int i = blockIdx.x*256 + threadIdx.x;
    if (i < 16384){ Wb2[i] = f2bf(W2[i]); Wb3[i] = f2bf(W3[i]); }
}

// ======== layer 1: gather 3-channel, thread per node ========
__global__ void k_gather3(const float* __restrict__ x, const int* __restrict__ rowptr,
                          const int2* __restrict__ edge, float* __restrict__ agg){
    int n = blockIdx.x * blockDim.x + threadIdx.x;
    if (n >= NN) return;
    int j0 = rowptr[n], j1 = rowptr[n + 1];
    float a0 = 0.f, a1 = 0.f, a2 = 0.f;
    for (int j = j0; j < j1; ++j){
        int2 e = edge[j];
        int r = e.x; float w = __int_as_float(e.y);
        a0 = fmaf(x[r*3+0], w, a0);
        a1 = fmaf(x[r*3+1], w, a1);
        a2 = fmaf(x[r*3+2], w, a2);
    }
    agg[n*3+0] = a0; agg[n*3+1] = a1; agg[n*3+2] = a2;
}

// ---- layer 1 dense + fused pool (h stored bf16; pool in fp32 pre-round) ----
__global__ __launch_bounds__(128) void k_dense3p(const float* __restrict__ agg, const float* __restrict__ W,
                          const float* __restrict__ b, ushort* __restrict__ h, float* __restrict__ part){
    int c = threadIdx.x;
    int n0 = blockIdx.x * 128;
    int n1 = min(n0 + 128, NN);
    float w0 = W[c*3+0], w1 = W[c*3+1], w2 = W[c*3+2], bb = b[c];
    float s = 0.f, m = -3.4e38f;
    for (int n = n0; n < n1; ++n){
        float v = fmaf(agg[n*3+0], w0, fmaf(agg[n*3+1], w1, fmaf(agg[n*3+2], w2, bb)));
        v = elu_f(v);
        h[(size_t)n*128 + c] = f2bf(v);
        s += v; m = fmaxf(m, v);
    }
    part[blockIdx.x*128 + c] = s;
    part[PMAX + blockIdx.x*128 + c] = m;
}

// ======== 128-channel gather (bf16 h): 16 lanes/node, 8 ch/lane ========
__global__ __launch_bounds__(256) void k_gather128(const ushort* __restrict__ h,
                              const int* __restrict__ rowptr, const int2* __restrict__ edge,
                              const float* __restrict__ att, ushort* __restrict__ aggB){
    int t = blockIdx.x * blockDim.x + threadIdx.x;
    int n = t >> 4, l = t & 15;
    if (n >= NN) return;
    int j0 = rowptr[n], j1 = rowptr[n + 1];
    float acc[8] = {0.f,0.f,0.f,0.f,0.f,0.f,0.f,0.f};
    int j = j0;
    for (; j + 3 < j1; j += 4){
        int2 e0 = edge[j], e1 = edge[j+1], e2 = edge[j+2], e3 = edge[j+3];
        bf16x8 v0 = *(const bf16x8*)(h + (size_t)e0.x*128 + l*8);
        bf16x8 v1 = *(const bf16x8*)(h + (size_t)e1.x*128 + l*8);
        bf16x8 v2 = *(const bf16x8*)(h + (size_t)e2.x*128 + l*8);
        bf16x8 v3 = *(const bf16x8*)(h + (size_t)e3.x*128 + l*8);
        float w0 = __int_as_float(e0.y), w1 = __int_as_float(e1.y);
        float w2 = __int_as_float(e2.y), w3 = __int_as_float(e3.y);
        #pragma unroll
        for (int c = 0; c < 8; ++c){
            acc[c] = fmaf(bf2f(v0[c]), w0, acc[c]);
            acc[c] = fmaf(bf2f(v1[c]), w1, acc[c]);
            acc[c] = fmaf(bf2f(v2[c]), w2, acc[c]);
            acc[c] = fmaf(bf2f(v3[c]), w3, acc[c]);
        }
    }
    for (; j < j1; ++j){
        int2 e0 = edge[j];
        bf16x8 v0 = *(const bf16x8*)(h + (size_t)e0.x*128 + l*8);
        float w0 = __int_as_float(e0.y);
        #pragma unroll
        for (int c = 0; c < 8; ++c)
            acc[c] = fmaf(bf2f(v0[c]), w0, acc[c]);
    }
    float4 a0 = ((const float4*)att)[l*2];
    float4 a1 = ((const float4*)att)[l*2+1];
    float av[8] = {a0.x,a0.y,a0.z,a0.w,a1.x,a1.y,a1.z,a1.w};
    bf16x8 o;
    #pragma unroll
    for (int c = 0; c < 8; ++c)
        o[c] = (short)f2bf(acc[c] * av[c]);
    *(bf16x8*)(aggB + (size_t)n*128 + l*8) = o;
}

// ---- pool partial pre-reduction ----
__global__ __launch_bounds__(256) void k_attn_pre(const float* __restrict__ part, int nblk,
                                                  float* __restrict__ part2){
    __shared__ float sS[2][128], sM[2][128];
    int c = threadIdx.x & 127, g = threadIdx.x >> 7;
    float s = 0.f, m = -3.4e38f;
    for (int b = blockIdx.x*2 + g; b < nblk; b += NRED*2){
        s += part[b*128 + c];
        m = fmaxf(m, part[PMAX + b*128 + c]);
    }
    sS[g][c] = s; sM[g][c] = m;
    __syncthreads();
    if (g == 0){
        part2[blockIdx.x*128 + c] = sS[0][c] + sS[1][c];
        part2[NRED*128 + blockIdx.x*128 + c] = fmaxf(sM[0][c], sM[1][c]);
    }
}

// ---- channel attention MLP ----
__global__ __launch_bounds__(512) void k_attn(const float* __restrict__ part2,
                       const float* __restrict__ w1, const float* __restrict__ w2,
                       float* __restrict__ att){
    __shared__ float sAll[4][128], mAll[4][128];
    __shared__ float avg[128], mx[128], ha[8], hm[8];
    int c = threadIdx.x & 127, g = threadIdx.x >> 7;
    float s = 0.f, m = -3.4e38f;
    #pragma unroll
    for (int b = 0; b < NRED/4; ++b){
        int r = b*4 + g;
        s += part2[r*128 + c];
        m = fmaxf(m, part2[NRED*128 + r*128 + c]);
    }
    sAll[g][c] = s; mAll[g][c] = m;
    __syncthreads();
    if (g == 0){
        s = sAll[0][c] + sAll[1][c] + sAll[2][c] + sAll[3][c];
        m = fmaxf(fmaxf(mAll[0][c], mAll[1][c]), fmaxf(mAll[2][c], mAll[3][c]));
        avg[c] = s / (float)NN;
        mx[c] = m;
    }
    __syncthreads();
    if (threadIdx.x < 8){
        int cc = threadIdx.x;
        float sa = 0.f, sm = 0.f;
        for (int k = 0; k < 128; ++k){
            float w = w1[cc*128 + k];
            sa += avg[k]*w; sm += mx[k]*w;
        }
        ha[cc] = fmaxf(sa, 0.f); hm[cc] = fmaxf(sm, 0.f);
    }
    __syncthreads();
    if (threadIdx.x < 128){
        float oa = 0.f, om = 0.f;
        for (int j = 0; j < 8; ++j){
            float w = w2[c*8 + j];
            oa += ha[j]*w; om += hm[j]*w;
        }
        att[c] = 1.f / (1.f + __expf(-(oa + om)));
    }
}

// ======== MFMA GEMM: h = ELU(aggB @ Wb^T + b) + fused pool; h stored bf16 ========
__global__ __launch_bounds__(256) void k_gemm_mfma(const ushort* __restrict__ aggB,
                        const ushort* __restrict__ Wb, const float* __restrict__ b,
                        ushort* __restrict__ h, float* __restrict__ part){
    __shared__ float poolS[4][128], poolM[4][128];
    int tid = threadIdx.x;
    int wave = tid >> 6, l = tid & 63;
    int lr = l & 15, lk = l >> 4;
    int n0 = blockIdx.x * 64 + wave * 16;

    bf16x8 a[4];
    const ushort* arow = aggB + (size_t)(n0 + lr) * 128 + lk * 8;
    #pragma unroll
    for (int kb = 0; kb < 4; ++kb)
        a[kb] = *(const bf16x8*)(arow + kb * 32);

    float s_part[8], m_part[8];
    const ushort* wbase = Wb + (size_t)lr * 128 + lk * 8;
    #pragma unroll
    for (int t = 0; t < 8; ++t){
        int j0 = t * 16;
        float bias = b[j0 + lr];
        f32x4 acc = {bias, bias, bias, bias};
        const ushort* wrow = wbase + (size_t)j0 * 128;
        #pragma unroll
        for (int kb = 0; kb < 4; ++kb){
            bf16x8 bf = *(const bf16x8*)(wrow + kb * 32);
            acc = __builtin_amdgcn_mfma_f32_16x16x32_bf16(a[kb], bf, acc, 0, 0, 0);
        }
        float s = 0.f, m = -3.4e38f;
        #pragma unroll
        for (int r = 0; r < 4; ++r){
            int n = n0 + lk * 4 + r;
            float v = elu_f(acc[r]);
            if (n < NN){
                h[(size_t)n * 128 + j0 + lr] = f2bf(v);
                s += v; m = fmaxf(m, v);
            }
        }
        s += __shfl_xor(s, 16); s += __shfl_xor(s, 32);
        m = fmaxf(m, __shfl_xor(m, 16)); m = fmaxf(m, __shfl_xor(m, 32));
        s_part[t] = s; m_part[t] = m;
    }
    if (lk == 0){
        #pragma unroll
        for (int t = 0; t < 8; ++t){
            poolS[wave][t * 16 + lr] = s_part[t];
            poolM[wave][t * 16 + lr] = m_part[t];
        }
    }
    __syncthreads();
    if (tid < 128){
        float S = poolS[0][tid] + poolS[1][tid] + poolS[2][tid] + poolS[3][tid];
        float M = fmaxf(fmaxf(poolM[0][tid], poolM[1][tid]), fmaxf(poolM[2][tid], poolM[3][tid]));
        part[blockIdx.x * 128 + tid] = S;
        part[PMAX + blockIdx.x * 128 + tid] = M;
    }
}

// ---- output head: thread per node, att folded ----
__global__ __launch_bounds__(256) void k_out(const ushort* __restrict__ h, const float* __restrict__ att,
                      const float* __restrict__ Wo, const float* __restrict__ bo,
                      float* __restrict__ out){
    int n = blockIdx.x * blockDim.x + threadIdx.x;
    if (n >= NN) return;
    float acc0 = bo[0], acc1 = bo[1], acc2 = bo[2];
    const bf16x8* hv = (const bf16x8*)(h + (size_t)n*128);
    #pragma unroll
    for (int i = 0; i < 16; ++i){
        bf16x8 v = hv[i];
        #pragma unroll
        for (int c = 0; c < 8; ++c){
            int cc = i*8 + c;
            float hv_f = bf2f(v[c]) * att[cc];
            acc0 = fmaf(hv_f, Wo[cc],        acc0);
            acc1 = fmaf(hv_f, Wo[128 + cc],  acc1);
            acc2 = fmaf(hv_f, Wo[256 + cc],  acc2);
        }
    }
    out[n*3+0] = acc0; out[n*3+1] = acc1; out[n*3+2] = acc2;
}

extern "C" void kernel_launch(void* const* d_in, const int* in_sizes, int n_in,
                              void* d_out, int out_size, void* d_ws, size_t ws_size,
                              hipStream_t stream) {
    const float* x    = (const float*)d_in[0];
    const int*   ei   = (const int*)d_in[1];
    const int*   row  = ei;
    const int*   col  = ei + NE;
    const float* dis  = (const float*)d_in[2];
    const float* W1   = (const float*)d_in[3];
    const float* b1   = (const float*)d_in[4];
    const float* W2   = (const float*)d_in[5];
    const float* b2   = (const float*)d_in[6];
    const float* W3   = (const float*)d_in[7];
    const float* b3   = (const float*)d_in[8];
    const float* ca1w1= (const float*)d_in[9];
    const float* ca1w2= (const float*)d_in[10];
    const float* ca2w1= (const float*)d_in[11];
    const float* ca2w2= (const float*)d_in[12];
    const float* ca3w1= (const float*)d_in[13];
    const float* ca3w2= (const float*)d_in[14];
    const float* Wout = (const float*)d_in[15];
    const float* bout = (const float*)d_in[16];
    float* out = (float*)d_out;

    ushort* hB    = (ushort*)d_ws;                        // [NN,128] bf16 h
    ushort* aggB  = hB + (size_t)NN*128;                  // [NPAD,128] bf16
    float*  agg3  = (float*)(aggB + (size_t)NPAD*128);    // [NN,3]
    float*  part  = agg3 + (size_t)NN*3;                  // 2*PMAX
    float*  part2 = part + (size_t)2*PMAX;                // 2*NRED*128
    float*  att1  = part2 + 2*NRED*128;
    float*  att2  = att1 + 128;
    float*  att3  = att2 + 128;
    ushort* Wb2   = (ushort*)(att3 + 128);                // [128,128] bf16
    ushort* Wb3   = Wb2 + 16384;
    int2*   edge  = (int2*)(Wb3 + 16384);                 // [NE]
    int*    rowptr= (int*)(edge + NE);                    // [NN+1]
    int*    deg   = rowptr + NN + 1;
    int*    cursor= deg + NN;
    int*    bsum  = cursor + NN;
    int*    boff  = bsum + NB1;

    const int gath_blocks = (NN * 16) / 256;              // 3125

    // ---- CSR build + weight conversion ----
    hipMemsetAsync(deg, 0, (size_t)NN * 2 * sizeof(int), stream);
    k_hist<<<(NE+255)/256, 256, 0, stream>>>(col, deg);
    k_convW<<<64, 256, 0, stream>>>(W2, W3, Wb2, Wb3);
    k_psum<<<NB1, 256, 0, stream>>>(deg, bsum);
    k_pscan<<<1, 256, 0, stream>>>(bsum, boff, rowptr);
    k_rowptr<<<NB1, 256, 0, stream>>>(deg, boff, rowptr);
    k_fill<<<(NE+255)/256, 256, 0, stream>>>(row, col, dis, rowptr, cursor, edge);

    // ---- layer 1 ----
    k_gather3<<<(NN+255)/256, 256, 0, stream>>>(x, rowptr, edge, agg3);
    k_dense3p<<<NBD3, 128, 0, stream>>>(agg3, W1, b1, hB, part);
    k_attn_pre<<<NRED, 256, 0, stream>>>(part, NBD3, part2);
    k_attn<<<1, 512, 0, stream>>>(part2, ca1w1, ca1w2, att1);

    // ---- layer 2 ----
    k_gather128<<<gath_blocks, 256, 0, stream>>>(hB, rowptr, edge, att1, aggB);
    k_gemm_mfma<<<NBG, 256, 0, stream>>>(aggB, Wb2, b2, hB, part);
    k_attn_pre<<<NRED, 256, 0, stream>>>(part, NBG, part2);
    k_attn<<<1, 512, 0, stream>>>(part2, ca2w1, ca2w2, att2);

    // ---- layer 3 ----
    k_gather128<<<gath_blocks, 256, 0, stream>>>(hB, rowptr, edge, att2, aggB);
    k_gemm_mfma<<<NBG, 256, 0, stream>>>(aggB, Wb3, b3, hB, part);
    k_attn_pre<<<NRED, 256, 0, stream>>>(part, NBG, part2);
    k_attn<<<1, 512, 0, stream>>>(part2, ca3w1, ca3w2, att3);

    // ---- output head (att3 folded in) ----
    k_out<<<(NN+255)/256, 256, 0, stream>>>(hB, att3, Wout, bout, out);
}

// Round 7
// 217.557 us; speedup vs baseline: 2.8855x; 1.2549x over previous
//
#include <hip/hip_runtime.h>

#define NN 50000
#define NE 800000
#define NPAD 50176                  // NN padded to multiple of 64
#define NBD3 391                    // ceil(NN/128) dense3 blocks
#define NBG 782                     // ceil(NN/64) mfma-gemm blocks
#define PMAX (NBG*128)              // offset of max-partials in part buffer
#define NRED 64                     // reduced partial rows after k_attn_pre

// ---- counting-sort CSR build params ----
#define EC 4096                     // edges per chunk block
#define NBLKC 196                   // ceil(NE/EC)
#define NBUCK 1563                  // ceil(NN/32), 32 nodes per bucket
#define LT (NBUCK*NBLKC)            // hist entries = 306348
#define NS1 300                     // ceil(LT/1024) scan blocks
#define DCAP 1024                   // LDS staging cap in k_dsort

typedef __attribute__((ext_vector_type(8))) short bf16x8;
typedef __attribute__((ext_vector_type(4))) float f32x4;

__device__ __forceinline__ float elu_f(float x){ return x > 0.f ? x : __expf(x) - 1.f; }

__device__ __forceinline__ ushort f2bf(float f){
    unsigned u = __float_as_uint(f);
    unsigned r = (u + 0x7FFFu + ((u >> 16) & 1u)) >> 16;
    return (ushort)r;
}
__device__ __forceinline__ float bf2f(short u){
    return __uint_as_float(((unsigned)(unsigned short)u) << 16);
}

// ======== Pass A: per-chunk bucket histogram (+ folded weight conversion) ========
__global__ __launch_bounds__(256) void k_bhist(const int* __restrict__ col, int* __restrict__ hist,
                        const float* __restrict__ W2, const float* __restrict__ W3,
                        ushort* __restrict__ Wb2, ushort* __restrict__ Wb3){
    int blk = blockIdx.x;
    if (blk >= NBLKC){                       // convW rider blocks
        int i = (blk - NBLKC)*256 + threadIdx.x;
        if (i < 16384){ Wb2[i] = f2bf(W2[i]); Wb3[i] = f2bf(W3[i]); }
        return;
    }
    __shared__ int h[NBUCK];
    for (int i = threadIdx.x; i < NBUCK; i += 256) h[i] = 0;
    __syncthreads();
    int base = blk * EC;
    #pragma unroll
    for (int i = 0; i < 16; ++i){
        int e = base + i*256 + threadIdx.x;
        if (e < NE) atomicAdd(&h[col[e] >> 5], 1);
    }
    __syncthreads();
    for (int i = threadIdx.x; i < NBUCK; i += 256) hist[i*NBLKC + blk] = h[i];
}

// ======== scan phase 1: 1024-chunk partial sums ========
__global__ __launch_bounds__(256) void k_s1(const int* __restrict__ hist, int* __restrict__ bsum){
    __shared__ int red[256];
    int base = blockIdx.x*1024 + threadIdx.x;
    int s = 0;
    #pragma unroll
    for (int i = 0; i < 4; ++i){ int idx = base + i*256; if (idx < LT) s += hist[idx]; }
    red[threadIdx.x] = s;
    __syncthreads();
    for (int off = 128; off > 0; off >>= 1){
        if (threadIdx.x < off) red[threadIdx.x] += red[threadIdx.x + off];
        __syncthreads();
    }
    if (threadIdx.x == 0) bsum[blockIdx.x] = red[0];
}

// ======== scan phase 2: scan NS1 partials ========
__global__ __launch_bounds__(512) void k_s2(const int* __restrict__ bsum, int* __restrict__ boff){
    __shared__ int s[512];
    int t = threadIdx.x;
    int v = (t < NS1) ? bsum[t] : 0;
    s[t] = v;
    __syncthreads();
    for (int off = 1; off < 512; off <<= 1){
        int u = (t >= off) ? s[t - off] : 0;
        __syncthreads();
        s[t] += u;
        __syncthreads();
    }
    if (t < NS1) boff[t] = s[t] - v;
}

// ======== scan phase 3: local scan + base -> scanned offsets + bucketPtr ========
__global__ __launch_bounds__(256) void k_s3(const int* __restrict__ hist, const int* __restrict__ boff,
                                            int* __restrict__ scanned, int* __restrict__ bucketPtr){
    __shared__ int red[256];
    int blk = blockIdx.x, t = threadIdx.x;
    int base = blk*1024;
    int v[4]; int s = 0;
    #pragma unroll
    for (int i = 0; i < 4; ++i){
        int idx = base + t*4 + i;
        v[i] = (idx < LT) ? hist[idx] : 0;
        s += v[i];
    }
    red[t] = s;
    __syncthreads();
    for (int off = 1; off < 256; off <<= 1){
        int u = (t >= off) ? red[t - off] : 0;
        __syncthreads();
        red[t] += u;
        __syncthreads();
    }
    int run = boff[blk] + red[t] - s;
    #pragma unroll
    for (int i = 0; i < 4; ++i){
        int idx = base + t*4 + i;
        if (idx < LT){
            scanned[idx] = run;
            if (idx % NBLKC == 0) bucketPtr[idx / NBLKC] = run;
            run += v[i];
        }
    }
    if (blk == 0 && t == 0) bucketPtr[NBUCK] = NE;
}

// ======== Pass C: bucket-sort edges (LDS cursors, no global atomics) ========
__global__ __launch_bounds__(256) void k_csort(const int* __restrict__ row, const int* __restrict__ col,
                                               const int* __restrict__ scanned, int2* __restrict__ edgeS){
    __shared__ int curs[NBUCK];
    int blk = blockIdx.x;
    for (int i = threadIdx.x; i < NBUCK; i += 256) curs[i] = scanned[i*NBLKC + blk];
    __syncthreads();
    int base = blk * EC;
    #pragma unroll
    for (int i = 0; i < 16; ++i){
        int e = base + i*256 + threadIdx.x;
        if (e < NE){
            int r = row[e], c = col[e];
            int pos = atomicAdd(&curs[c >> 5], 1);
            edgeS[pos] = make_int2(r, c);
        }
    }
}

// ======== Pass D: in-bucket per-node sort + nrm + rowptr (in-place, LDS staged) ========
__global__ __launch_bounds__(256) void k_dsort(const float* __restrict__ dis, const int* __restrict__ bucketPtr,
                                               int2* __restrict__ edge, int* __restrict__ rowptr){
    __shared__ int nodeCnt[32];
    __shared__ int nodeOff[33];
    __shared__ float disL[32];
    __shared__ int2 stage[DCAP];
    int b = blockIdx.x, t = threadIdx.x;
    int j0 = bucketPtr[b], j1 = bucketPtr[b+1], cnt = j1 - j0;
    if (t < 32){
        nodeCnt[t] = 0;
        int c = b*32 + t;
        disL[t] = (c < NN) ? dis[c] : 0.f;
    }
    __syncthreads();
    int er[8], ec[8], rk[8]; int m = 0;
    for (int j = t; j < cnt && m < 8; j += 256){
        int2 e = edge[j0 + j];
        int cl = e.y & 31;
        er[m] = e.x; ec[m] = e.y;
        rk[m] = atomicAdd(&nodeCnt[cl], 1);
        ++m;
    }
    __syncthreads();
    if (t == 0){
        int run = 0;
        #pragma unroll
        for (int i = 0; i < 32; ++i){ nodeOff[i] = run; run += nodeCnt[i]; }
        nodeOff[32] = run;
    }
    __syncthreads();
    if (t < 32){
        int c = b*32 + t;
        if (c < NN) rowptr[c] = j0 + nodeOff[t];
    }
    if (b == 0 && t == 0) rowptr[NN] = NE;
    bool staged = (cnt <= DCAP);
    for (int i = 0; i < m; ++i){
        int r = er[i], cl = ec[i] & 31;
        float nm = dis[r] * disL[cl];
        int pos = nodeOff[cl] + rk[i];
        int2 rec = make_int2(r, __float_as_int(nm));
        if (staged) stage[pos] = rec;
        else        edge[j0 + pos] = rec;      // reads all done before first barrier
    }
    __syncthreads();
    if (staged)
        for (int j = t; j < cnt; j += 256) edge[j0 + j] = stage[j];
}

// ======== layer 1: gather 3-channel, thread per node ========
__global__ void k_gather3(const float* __restrict__ x, const int* __restrict__ rowptr,
                          const int2* __restrict__ edge, float* __restrict__ agg){
    int n = blockIdx.x * blockDim.x + threadIdx.x;
    if (n >= NN) return;
    int j0 = rowptr[n], j1 = rowptr[n + 1];
    float a0 = 0.f, a1 = 0.f, a2 = 0.f;
    for (int j = j0; j < j1; ++j){
        int2 e = edge[j];
        int r = e.x; float w = __int_as_float(e.y);
        a0 = fmaf(x[r*3+0], w, a0);
        a1 = fmaf(x[r*3+1], w, a1);
        a2 = fmaf(x[r*3+2], w, a2);
    }
    agg[n*3+0] = a0; agg[n*3+1] = a1; agg[n*3+2] = a2;
}

// ---- layer 1 dense + fused pool (h stored bf16; pool in fp32 pre-round) ----
__global__ __launch_bounds__(128) void k_dense3p(const float* __restrict__ agg, const float* __restrict__ W,
                          const float* __restrict__ b, ushort* __restrict__ h, float* __restrict__ part){
    int c = threadIdx.x;
    int n0 = blockIdx.x * 128;
    int n1 = min(n0 + 128, NN);
    float w0 = W[c*3+0], w1 = W[c*3+1], w2 = W[c*3+2], bb = b[c];
    float s = 0.f, m = -3.4e38f;
    for (int n = n0; n < n1; ++n){
        float v = fmaf(agg[n*3+0], w0, fmaf(agg[n*3+1], w1, fmaf(agg[n*3+2], w2, bb)));
        v = elu_f(v);
        h[(size_t)n*128 + c] = f2bf(v);
        s += v; m = fmaxf(m, v);
    }
    part[blockIdx.x*128 + c] = s;
    part[PMAX + blockIdx.x*128 + c] = m;
}

// ======== 128-channel gather (bf16 h): 16 lanes/node, 8 ch/lane ========
__global__ __launch_bounds__(256) void k_gather128(const ushort* __restrict__ h,
                              const int* __restrict__ rowptr, const int2* __restrict__ edge,
                              const float* __restrict__ att, ushort* __restrict__ aggB){
    int t = blockIdx.x * blockDim.x + threadIdx.x;
    int n = t >> 4, l = t & 15;
    if (n >= NN) return;
    int j0 = rowptr[n], j1 = rowptr[n + 1];
    float acc[8] = {0.f,0.f,0.f,0.f,0.f,0.f,0.f,0.f};
    int j = j0;
    for (; j + 3 < j1; j += 4){
        int2 e0 = edge[j], e1 = edge[j+1], e2 = edge[j+2], e3 = edge[j+3];
        bf16x8 v0 = *(const bf16x8*)(h + (size_t)e0.x*128 + l*8);
        bf16x8 v1 = *(const bf16x8*)(h + (size_t)e1.x*128 + l*8);
        bf16x8 v2 = *(const bf16x8*)(h + (size_t)e2.x*128 + l*8);
        bf16x8 v3 = *(const bf16x8*)(h + (size_t)e3.x*128 + l*8);
        float w0 = __int_as_float(e0.y), w1 = __int_as_float(e1.y);
        float w2 = __int_as_float(e2.y), w3 = __int_as_float(e3.y);
        #pragma unroll
        for (int c = 0; c < 8; ++c){
            acc[c] = fmaf(bf2f(v0[c]), w0, acc[c]);
            acc[c] = fmaf(bf2f(v1[c]), w1, acc[c]);
            acc[c] = fmaf(bf2f(v2[c]), w2, acc[c]);
            acc[c] = fmaf(bf2f(v3[c]), w3, acc[c]);
        }
    }
    for (; j < j1; ++j){
        int2 e0 = edge[j];
        bf16x8 v0 = *(const bf16x8*)(h + (size_t)e0.x*128 + l*8);
        float w0 = __int_as_float(e0.y);
        #pragma unroll
        for (int c = 0; c < 8; ++c)
            acc[c] = fmaf(bf2f(v0[c]), w0, acc[c]);
    }
    float4 a0 = ((const float4*)att)[l*2];
    float4 a1 = ((const float4*)att)[l*2+1];
    float av[8] = {a0.x,a0.y,a0.z,a0.w,a1.x,a1.y,a1.z,a1.w};
    bf16x8 o;
    #pragma unroll
    for (int c = 0; c < 8; ++c)
        o[c] = (short)f2bf(acc[c] * av[c]);
    *(bf16x8*)(aggB + (size_t)n*128 + l*8) = o;
}

// ---- pool partial pre-reduction ----
__global__ __launch_bounds__(256) void k_attn_pre(const float* __restrict__ part, int nblk,
                                                  float* __restrict__ part2){
    __shared__ float sS[2][128], sM[2][128];
    int c = threadIdx.x & 127, g = threadIdx.x >> 7;
    float s = 0.f, m = -3.4e38f;
    for (int b = blockIdx.x*2 + g; b < nblk; b += NRED*2){
        s += part[b*128 + c];
        m = fmaxf(m, part[PMAX + b*128 + c]);
    }
    sS[g][c] = s; sM[g][c] = m;
    __syncthreads();
    if (g == 0){
        part2[blockIdx.x*128 + c] = sS[0][c] + sS[1][c];
        part2[NRED*128 + blockIdx.x*128 + c] = fmaxf(sM[0][c], sM[1][c]);
    }
}

// ---- channel attention MLP ----
__global__ __launch_bounds__(512) void k_attn(const float* __restrict__ part2,
                       const float* __restrict__ w1, const float* __restrict__ w2,
                       float* __restrict__ att){
    __shared__ float sAll[4][128], mAll[4][128];
    __shared__ float avg[128], mx[128], ha[8], hm[8];
    int c = threadIdx.x & 127, g = threadIdx.x >> 7;
    float s = 0.f, m = -3.4e38f;
    #pragma unroll
    for (int b = 0; b < NRED/4; ++b){
        int r = b*4 + g;
        s += part2[r*128 + c];
        m = fmaxf(m, part2[NRED*128 + r*128 + c]);
    }
    sAll[g][c] = s; mAll[g][c] = m;
    __syncthreads();
    if (g == 0){
        s = sAll[0][c] + sAll[1][c] + sAll[2][c] + sAll[3][c];
        m = fmaxf(fmaxf(mAll[0][c], mAll[1][c]), fmaxf(mAll[2][c], mAll[3][c]));
        avg[c] = s / (float)NN;
        mx[c] = m;
    }
    __syncthreads();
    if (threadIdx.x < 8){
        int cc = threadIdx.x;
        float sa = 0.f, sm = 0.f;
        for (int k = 0; k < 128; ++k){
            float w = w1[cc*128 + k];
            sa += avg[k]*w; sm += mx[k]*w;
        }
        ha[cc] = fmaxf(sa, 0.f); hm[cc] = fmaxf(sm, 0.f);
    }
    __syncthreads();
    if (threadIdx.x < 128){
        float oa = 0.f, om = 0.f;
        for (int j = 0; j < 8; ++j){
            float w = w2[c*8 + j];
            oa += ha[j]*w; om += hm[j]*w;
        }
        att[c] = 1.f / (1.f + __expf(-(oa + om)));
    }
}

// ======== MFMA GEMM: h = ELU(aggB @ Wb^T + b) + fused pool; h stored bf16 ========
__global__ __launch_bounds__(256) void k_gemm_mfma(const ushort* __restrict__ aggB,
                        const ushort* __restrict__ Wb, const float* __restrict__ b,
                        ushort* __restrict__ h, float* __restrict__ part){
    __shared__ float poolS[4][128], poolM[4][128];
    int tid = threadIdx.x;
    int wave = tid >> 6, l = tid & 63;
    int lr = l & 15, lk = l >> 4;
    int n0 = blockIdx.x * 64 + wave * 16;

    bf16x8 a[4];
    const ushort* arow = aggB + (size_t)(n0 + lr) * 128 + lk * 8;
    #pragma unroll
    for (int kb = 0; kb < 4; ++kb)
        a[kb] = *(const bf16x8*)(arow + kb * 32);

    float s_part[8], m_part[8];
    const ushort* wbase = Wb + (size_t)lr * 128 + lk * 8;
    #pragma unroll
    for (int t = 0; t < 8; ++t){
        int j0 = t * 16;
        float bias = b[j0 + lr];
        f32x4 acc = {bias, bias, bias, bias};
        const ushort* wrow = wbase + (size_t)j0 * 128;
        #pragma unroll
        for (int kb = 0; kb < 4; ++kb){
            bf16x8 bf = *(const bf16x8*)(wrow + kb * 32);
            acc = __builtin_amdgcn_mfma_f32_16x16x32_bf16(a[kb], bf, acc, 0, 0, 0);
        }
        float s = 0.f, m = -3.4e38f;
        #pragma unroll
        for (int r = 0; r < 4; ++r){
            int n = n0 + lk * 4 + r;
            float v = elu_f(acc[r]);
            if (n < NN){
                h[(size_t)n * 128 + j0 + lr] = f2bf(v);
                s += v; m = fmaxf(m, v);
            }
        }
        s += __shfl_xor(s, 16); s += __shfl_xor(s, 32);
        m = fmaxf(m, __shfl_xor(m, 16)); m = fmaxf(m, __shfl_xor(m, 32));
        s_part[t] = s; m_part[t] = m;
    }
    if (lk == 0){
        #pragma unroll
        for (int t = 0; t < 8; ++t){
            poolS[wave][t * 16 + lr] = s_part[t];
            poolM[wave][t * 16 + lr] = m_part[t];
        }
    }
    __syncthreads();
    if (tid < 128){
        float S = poolS[0][tid] + poolS[1][tid] + poolS[2][tid] + poolS[3][tid];
        float M = fmaxf(fmaxf(poolM[0][tid], poolM[1][tid]), fmaxf(poolM[2][tid], poolM[3][tid]));
        part[blockIdx.x * 128 + tid] = S;
        part[PMAX + blockIdx.x * 128 + tid] = M;
    }
}

// ---- output head: thread per node, att folded ----
__global__ __launch_bounds__(256) void k_out(const ushort* __restrict__ h, const float* __restrict__ att,
                      const float* __restrict__ Wo, const float* __restrict__ bo,
                      float* __restrict__ out){
    int n = blockIdx.x * blockDim.x + threadIdx.x;
    if (n >= NN) return;
    float acc0 = bo[0], acc1 = bo[1], acc2 = bo[2];
    const bf16x8* hv = (const bf16x8*)(h + (size_t)n*128);
    #pragma unroll
    for (int i = 0; i < 16; ++i){
        bf16x8 v = hv[i];
        #pragma unroll
        for (int c = 0; c < 8; ++c){
            int cc = i*8 + c;
            float hv_f = bf2f(v[c]) * att[cc];
            acc0 = fmaf(hv_f, Wo[cc],        acc0);
            acc1 = fmaf(hv_f, Wo[128 + cc],  acc1);
            acc2 = fmaf(hv_f, Wo[256 + cc],  acc2);
        }
    }
    out[n*3+0] = acc0; out[n*3+1] = acc1; out[n*3+2] = acc2;
}

extern "C" void kernel_launch(void* const* d_in, const int* in_sizes, int n_in,
                              void* d_out, int out_size, void* d_ws, size_t ws_size,
                              hipStream_t stream) {
    const float* x    = (const float*)d_in[0];
    const int*   ei   = (const int*)d_in[1];
    const int*   row  = ei;
    const int*   col  = ei + NE;
    const float* dis  = (const float*)d_in[2];
    const float* W1   = (const float*)d_in[3];
    const float* b1   = (const float*)d_in[4];
    const float* W2   = (const float*)d_in[5];
    const float* b2   = (const float*)d_in[6];
    const float* W3   = (const float*)d_in[7];
    const float* b3   = (const float*)d_in[8];
    const float* ca1w1= (const float*)d_in[9];
    const float* ca1w2= (const float*)d_in[10];
    const float* ca2w1= (const float*)d_in[11];
    const float* ca2w2= (const float*)d_in[12];
    const float* ca3w1= (const float*)d_in[13];
    const float* ca3w2= (const float*)d_in[14];
    const float* Wout = (const float*)d_in[15];
    const float* bout = (const float*)d_in[16];
    float* out = (float*)d_out;

    ushort* hB    = (ushort*)d_ws;                        // [NN,128] bf16 h
    ushort* aggB  = hB + (size_t)NN*128;                  // [NPAD,128] bf16
    float*  agg3  = (float*)(aggB + (size_t)NPAD*128);    // [NN,3]
    float*  part  = agg3 + (size_t)NN*3;                  // 2*PMAX
    float*  part2 = part + (size_t)2*PMAX;                // 2*NRED*128
    float*  att1  = part2 + 2*NRED*128;
    float*  att2  = att1 + 128;
    float*  att3  = att2 + 128;
    ushort* Wb2   = (ushort*)(att3 + 128);                // [128,128] bf16
    ushort* Wb3   = Wb2 + 16384;
    int2*   edge  = (int2*)(Wb3 + 16384);                 // [NE] (r,c) then (src,nrm)
    int*    rowptr= (int*)(edge + NE);                    // [NN+1]
    int*    hist  = rowptr + NN + 1;                      // [LT]
    int*    scanned = hist + LT;                          // [LT]
    int*    bucketPtr = scanned + LT;                     // [NBUCK+1]
    int*    bsum  = bucketPtr + NBUCK + 1;                // [NS1]
    int*    boff  = bsum + NS1;                           // [NS1]

    const int gath_blocks = (NN * 16) / 256;              // 3125

    // ---- CSR build: atomic-free two-level counting sort ----
    k_bhist<<<NBLKC + 64, 256, 0, stream>>>(col, hist, W2, W3, Wb2, Wb3);
    k_s1<<<NS1, 256, 0, stream>>>(hist, bsum);
    k_s2<<<1, 512, 0, stream>>>(bsum, boff);
    k_s3<<<NS1, 256, 0, stream>>>(hist, boff, scanned, bucketPtr);
    k_csort<<<NBLKC, 256, 0, stream>>>(row, col, scanned, edge);
    k_dsort<<<NBUCK, 256, 0, stream>>>(dis, bucketPtr, edge, rowptr);

    // ---- layer 1 ----
    k_gather3<<<(NN+255)/256, 256, 0, stream>>>(x, rowptr, edge, agg3);
    k_dense3p<<<NBD3, 128, 0, stream>>>(agg3, W1, b1, hB, part);
    k_attn_pre<<<NRED, 256, 0, stream>>>(part, NBD3, part2);
    k_attn<<<1, 512, 0, stream>>>(part2, ca1w1, ca1w2, att1);

    // ---- layer 2 ----
    k_gather128<<<gath_blocks, 256, 0, stream>>>(hB, rowptr, edge, att1, aggB);
    k_gemm_mfma<<<NBG, 256, 0, stream>>>(aggB, Wb2, b2, hB, part);
    k_attn_pre<<<NRED, 256, 0, stream>>>(part, NBG, part2);
    k_attn<<<1, 512, 0, stream>>>(part2, ca2w1, ca2w2, att2);

    // ---- layer 3 ----
    k_gather128<<<gath_blocks, 256, 0, stream>>>(hB, rowptr, edge, att2, aggB);
    k_gemm_mfma<<<NBG, 256, 0, stream>>>(aggB, Wb3, b3, hB, part);
    k_attn_pre<<<NRED, 256, 0, stream>>>(part, NBG, part2);
    k_attn<<<1, 512, 0, stream>>>(part2, ca3w1, ca3w2, att3);

    // ---- output head (att3 folded in) ----
    k_out<<<(NN+255)/256, 256, 0, stream>>>(hB, att3, Wout, bout, out);
}